// Round 1
// baseline (93.243 us; speedup 1.0000x reference)
//
#include <hip/hip_runtime.h>

// Problem constants (match reference)
constexpr int B = 32, S = 4096, D = 64;
constexpr int NC = 128;          // chunks per sequence
constexpr int L  = S / NC;       // 32 steps per chunk
constexpr float EPS_DIV = 1e-8f;
constexpr float EPS_LN  = 1e-5f;

// 64-lane butterfly sum of two values simultaneously
__device__ __forceinline__ void wsum2(float& x, float& y) {
#pragma unroll
    for (int m = 1; m < 64; m <<= 1) {
        x += __shfl_xor(x, m, 64);
        y += __shfl_xor(y, m, 64);
    }
}

__device__ __forceinline__ float sigmoid_f(float x) {
    // |x| is small (W*0.5, W~N(0,1)); rcp+exp are ~1ulp — fine vs 0.158 threshold
    return __builtin_amdgcn_rcpf(1.f + __expf(-x));
}

// ---------------- Phase 1: per-chunk affine summaries ----------------
// For each (batch, chunk): run recurrence with zero carry, producing
//   scalar: M = prod(m_s), Q = sum_i (prod_{j>i} m_j) q_i
//   vector: P[d] = prod(decay), O[d] analogous
// Also store per-step (m, q) so phase 3 needs no first butterfly.
__global__ __launch_bounds__(256) void k_phase1(
    const float* __restrict__ Cp, const float* __restrict__ Vp,
    const float* __restrict__ Wp, const float* __restrict__ TM,
    float2* __restrict__ MQstep,                  // [B*S]
    float*  __restrict__ Mc, float* __restrict__ Qc,   // [B*NC]
    float*  __restrict__ Pc, float* __restrict__ Oc)   // [B*NC*D]
{
    const int w    = blockIdx.x * 4 + (threadIdx.x >> 6);
    const int lane = threadIdx.x & 63;
    const int b    = w >> 7;            // w / NC  (NC==128)
    const int c    = w & (NC - 1);
    const int s0   = c * L;
    const size_t base = ((size_t)b * S + s0) * D + lane;
    const float tm = TM[lane];

    float M = 1.f, Q = 0.f, Pd = 1.f, Ob = 0.f;
#pragma unroll 4
    for (int i = 0; i < L; ++i) {
        const size_t idx = base + (size_t)i * D;
        const float wv = Wp[idx], cv = Cp[idx], vv = Vp[idx];
        const float dg = sigmoid_f(wv * tm);
        const float ec = __expf(cv);
        float sd = dg, se = ec;
        wsum2(sd, se);                       // sum(decay), sum(exp)
        const float m = sd * (1.f / 64.f);   // mean(decay)
        if (lane == 0)
            MQstep[(size_t)b * S + s0 + i] = make_float2(m, se);
        M *= m;
        Q  = fmaf(m, Q, se);
        Pd *= dg;
        Ob = fmaf(dg, Ob, ec * vv);
    }
    const int e = b * NC + c;
    if (lane == 0) { Mc[e] = M; Qc[e] = Q; }
    Pc[(size_t)e * D + lane] = Pd;
    Oc[(size_t)e * D + lane] = Ob;
}

// ---------------- Phase 2: scan chunk summaries -> carry-in per chunk ----------------
__global__ __launch_bounds__(64) void k_phase2(
    const float* __restrict__ Mc, const float* __restrict__ Qc,
    const float* __restrict__ Pc, const float* __restrict__ Oc,
    float* __restrict__ aIn, float* __restrict__ bIn)
{
    const int b = blockIdx.x;
    const int lane = threadIdx.x;
    float a = 0.f, bv = 0.f;
    for (int c = 0; c < NC; ++c) {
        const int e = b * NC + c;
        if (lane == 0) aIn[e] = a;
        bIn[(size_t)e * D + lane] = bv;
        const float m = Mc[e], q = Qc[e];
        const float p = Pc[(size_t)e * D + lane];
        const float o = Oc[(size_t)e * D + lane];
        a  = fmaf(m, a, q);
        bv = fmaf(p, bv, o);
    }
}

// ---------------- Phase 3: replay with known carry, fused LayerNorm ----------------
__global__ __launch_bounds__(256) void k_phase3(
    const float* __restrict__ Cp, const float* __restrict__ Vp,
    const float* __restrict__ Wp, const float* __restrict__ TM,
    const float* __restrict__ Gam, const float* __restrict__ Bet,
    const float2* __restrict__ MQstep,
    const float* __restrict__ aIn, const float* __restrict__ bIn,
    float* __restrict__ out)
{
    const int w    = blockIdx.x * 4 + (threadIdx.x >> 6);
    const int lane = threadIdx.x & 63;
    const int b    = w >> 7;
    const int c    = w & (NC - 1);
    const int e    = b * NC + c;
    const int s0   = c * L;
    const size_t base = ((size_t)b * S + s0) * D + lane;
    const float tm = TM[lane], g = Gam[lane], bt = Bet[lane];

    float a  = aIn[e];                       // uniform broadcast load
    float bv = bIn[(size_t)e * D + lane];
#pragma unroll 4
    for (int i = 0; i < L; ++i) {
        const size_t idx = base + (size_t)i * D;
        const float wv = Wp[idx], cv = Cp[idx], vv = Vp[idx];
        const float dg = sigmoid_f(wv * tm);
        const float ec = __expf(cv);
        const float2 mq = MQstep[(size_t)b * S + s0 + i];  // uniform
        a  = fmaf(mq.x, a, mq.y);            // carried dep: 1 FMA
        bv = fmaf(dg, bv, ec * vv);          // carried dep: 1 FMA
        const float y = bv * __builtin_amdgcn_rcpf(a + EPS_DIV);
        float sy = y, sq = y * y;
        wsum2(sy, sq);                       // LN reduce
        const float mu  = sy * (1.f / 64.f);
        const float var = fmaf(-mu, mu, sq * (1.f / 64.f));
        const float rs  = __builtin_amdgcn_rsqf(fmaxf(var, 0.f) + EPS_LN);
        out[idx] = fmaf((y - mu) * rs, g, bt);
    }
}

// ---------------- Fallback (only if workspace unexpectedly small) ----------------
__global__ __launch_bounds__(64) void k_naive(
    const float* __restrict__ Cp, const float* __restrict__ Vp,
    const float* __restrict__ Wp, const float* __restrict__ TM,
    const float* __restrict__ Gam, const float* __restrict__ Bet,
    float* __restrict__ out)
{
    const int b = blockIdx.x;
    const int lane = threadIdx.x;
    const float tm = TM[lane], g = Gam[lane], bt = Bet[lane];
    float a = 0.f, bv = 0.f;
    for (int s = 0; s < S; ++s) {
        const size_t idx = ((size_t)b * S + s) * D + lane;
        const float wv = Wp[idx], cv = Cp[idx], vv = Vp[idx];
        const float dg = sigmoid_f(wv * tm);
        const float ec = __expf(cv);
        float sd = dg, se = ec;
        wsum2(sd, se);
        a  = fmaf(sd * (1.f / 64.f), a, se);
        bv = fmaf(dg, bv, ec * vv);
        const float y = bv * __builtin_amdgcn_rcpf(a + EPS_DIV);
        float sy = y, sq = y * y;
        wsum2(sy, sq);
        const float mu  = sy * (1.f / 64.f);
        const float var = fmaf(-mu, mu, sq * (1.f / 64.f));
        const float rs  = __builtin_amdgcn_rsqf(fmaxf(var, 0.f) + EPS_LN);
        out[idx] = fmaf((y - mu) * rs, g, bt);
    }
}

extern "C" void kernel_launch(void* const* d_in, const int* in_sizes, int n_in,
                              void* d_out, int out_size, void* d_ws, size_t ws_size,
                              hipStream_t stream) {
    const float* Cp  = (const float*)d_in[0];
    const float* Vp  = (const float*)d_in[1];
    const float* Wp  = (const float*)d_in[2];
    const float* TM  = (const float*)d_in[3];
    const float* Gam = (const float*)d_in[4];
    const float* Bet = (const float*)d_in[5];
    float* out = (float*)d_out;

    // Workspace layout (floats):
    //   MQstep : B*S*2            (per-step mean-decay + sum-exp)
    //   Mc, Qc : B*NC each
    //   Pc, Oc : B*NC*D each
    //   aIn    : B*NC
    //   bIn    : B*NC*D
    const size_t f_mq  = (size_t)B * S * 2;
    const size_t f_sc  = (size_t)B * NC;
    const size_t f_vec = (size_t)B * NC * D;
    const size_t need_bytes = (f_mq + 3 * f_sc + 3 * f_vec) * sizeof(float);

    if (ws_size < need_bytes) {
        // Safe (slow) path: one wave per batch, fully sequential scan.
        k_naive<<<dim3(B), dim3(64), 0, stream>>>(Cp, Vp, Wp, TM, Gam, Bet, out);
        return;
    }

    float* wsf = (float*)d_ws;
    float2* MQstep = (float2*)wsf;
    float* Mc  = wsf + f_mq;
    float* Qc  = Mc + f_sc;
    float* Pc  = Qc + f_sc;
    float* Oc  = Pc + f_vec;
    float* aIn = Oc + f_vec;
    float* bIn = aIn + f_sc;

    const int waves = B * NC;           // 4096
    const dim3 blk(256);                // 4 waves/block
    const dim3 grd(waves / 4);          // 1024 blocks

    k_phase1<<<grd, blk, 0, stream>>>(Cp, Vp, Wp, TM, MQstep, Mc, Qc, Pc, Oc);
    k_phase2<<<dim3(B), dim3(64), 0, stream>>>(Mc, Qc, Pc, Oc, aIn, bIn);
    k_phase3<<<grd, blk, 0, stream>>>(Cp, Vp, Wp, TM, Gam, Bet, MQstep, aIn, bIn, out);
}